// Round 5
// baseline (1769.869 us; speedup 1.0000x reference)
//
#include <hip/hip_runtime.h>

// LSTM B=512,T=512,D=128,H=64,O=1. Gate order i,f,g,o.
// K1: pre[b][t][0..255] = x[b,t,:]@Wih0^T + bih0+bhh0 (fp32 VALU GEMM, unchanged).
// K2: fused 2-layer recurrence on MFMA (bf16x3 split for ~fp32 accuracy).
//   32 blocks x 16 batch x 256 thr (4 waves, 1 wave/SIMD, launch_bounds(256,1)
//   so the 192 weight-fragment VGPRs stay resident — Round3/4 regression was
//   the compiler demoting weight registers to per-step L2 reloads).
//   Wave w owns n-tiles {w,w+4,w+8,w+12} = gates i,f,g,o of cols [16w,16w+16):
//   C/D layout (row=(l>>4)*4+reg=batch, col=l&15) => all 4 gates of a
//   (batch,hidden) pair land in one lane; c,h updates fully in-register.
//   h crosses waves via LDS as pre-swizzled bf16 hi/lo A-fragments (~12KB/wave/step).

#define TSTEPS 512

typedef __attribute__((ext_vector_type(8))) short bfrag;   // 8 bf16 = 4 VGPR
typedef __attribute__((ext_vector_type(4))) float facc;    // 4 f32

__device__ __forceinline__ float sigf(float x){ return 1.0f/(1.0f+__expf(-x)); }
__device__ __forceinline__ float tanh_fast(float x){
  float ax=fabsf(x); float e=__expf(-2.0f*ax); float r=(1.0f-e)/(1.0f+e); return copysignf(r,x);
}
__device__ __forceinline__ unsigned short f2bf(float x){
  unsigned u=__float_as_uint(x); return (unsigned short)((u + 0x7FFFu + ((u>>16)&1u))>>16);
}
__device__ __forceinline__ float bf2f(unsigned short h){ return __uint_as_float(((unsigned)h)<<16); }

#define MFMA(a,b,c) __builtin_amdgcn_mfma_f32_16x16x32_bf16((a),(b),(c),0,0,0)

// ---------------- K1: input projection GEMM (fp32 VALU) ----------------
__global__ __launch_bounds__(256) void k_inproj(
    const float* __restrict__ x, const float* __restrict__ W,
    const float* __restrict__ bih, const float* __restrict__ bhh,
    float* __restrict__ pre)
{
    __shared__ float xs[64][128];
    const int tid = threadIdx.x;
    const long row0 = (long)blockIdx.x * 64;

    const float4* __restrict__ xv = (const float4*)(x + row0 * 128);
    float4* xsv = (float4*)(&xs[0][0]);
#pragma unroll
    for (int i = 0; i < 8; ++i) xsv[tid + 256 * i] = xv[tid + 256 * i];
    __syncthreads();

    const int tx = tid & 63;
    const int ty = tid >> 6;

    float acc[16][4];
#pragma unroll
    for (int i = 0; i < 16; ++i)
#pragma unroll
        for (int j = 0; j < 4; ++j) acc[i][j] = 0.0f;

#pragma unroll 1
    for (int kc = 0; kc < 16; ++kc) {
        const int k0 = kc * 8;
        float4 w0[4], w1[4];
#pragma unroll
        for (int j = 0; j < 4; ++j) {
            const float* wr = W + (tx + 64 * j) * 128 + k0;
            w0[j] = *(const float4*)wr;
            w1[j] = *(const float4*)(wr + 4);
        }
#pragma unroll
        for (int i = 0; i < 16; ++i) {
            const int r = ty * 16 + i;
            float4 a0 = *(const float4*)(&xs[r][k0]);
            float4 a1 = *(const float4*)(&xs[r][k0 + 4]);
#pragma unroll
            for (int j = 0; j < 4; ++j) {
                float s = acc[i][j];
                s = fmaf(a0.x, w0[j].x, s); s = fmaf(a0.y, w0[j].y, s);
                s = fmaf(a0.z, w0[j].z, s); s = fmaf(a0.w, w0[j].w, s);
                s = fmaf(a1.x, w1[j].x, s); s = fmaf(a1.y, w1[j].y, s);
                s = fmaf(a1.z, w1[j].z, s); s = fmaf(a1.w, w1[j].w, s);
                acc[i][j] = s;
            }
        }
    }

    float bsum[4];
#pragma unroll
    for (int j = 0; j < 4; ++j) { const int g = tx + 64 * j; bsum[j] = bih[g] + bhh[g]; }
#pragma unroll
    for (int i = 0; i < 16; ++i) {
        const long r = row0 + ty * 16 + i;
        float* pr = pre + r * 256;
#pragma unroll
        for (int j = 0; j < 4; ++j) pr[tx + 64 * j] = acc[i][j] + bsum[j];
    }
}

// ---------------- K2: fused MFMA recurrence ----------------
// A-frag layout assumed (matches verified C/D family): lane l holds
// A[l&15][(l>>4)*8 + e]; B[k][n]: lane l holds B[(l>>4)*8+e][l&15].
__global__ __launch_bounds__(256, 1) void k_fused(
    const float* __restrict__ Whh0, const float* __restrict__ Wih1,
    const float* __restrict__ Whh1,
    const float* __restrict__ bih1, const float* __restrict__ bhh1,
    const float* __restrict__ Wfc,  const float* __restrict__ bfc,
    const float* __restrict__ pre,  float* __restrict__ out)
{
    const int tid  = threadIdx.x;
    const int w    = tid >> 6;          // wave 0..3
    const int lane = tid & 63;
    const int lm   = lane & 15;         // n-col within tile / A row (m)
    const int lk   = lane >> 4;         // k-group
    const int bbase = blockIdx.x * 16;  // 16 batch elems per block

    // LDS: h as pre-swizzled bf16 A-fragments. [parity][part hi/lo][ks][lane][8]
    __shared__ __align__(16) short hbuf0[2][2][2][64][8];
    __shared__ __align__(16) short hbuf1[2][2][2][64][8];
    __shared__ float hfin[16][64];
    __shared__ float psum[16][16];

    // zero parity-0 buffers (h_{-1}=0)
    {
        int* z0 = (int*)&hbuf0[0][0][0][0][0];
        int* z1 = (int*)&hbuf1[0][0][0][0][0];
#pragma unroll
        for (int i = 0; i < 4; ++i) { z0[tid + 256 * i] = 0; z1[tid + 256 * i] = 0; }
    }

    // ---- weight B-fragments in registers (bf16 hi/lo), 192 VGPRs ----
    bfrag w0h[4][2], w0l[4][2], w1h[4][2], w1l[4][2], w2h[4][2], w2l[4][2];
#pragma unroll
    for (int gi = 0; gi < 4; ++gi) {
        const int n = (w + 4 * gi) * 16 + lm;   // gate-col = 64*gi + 16*w + lm
#pragma unroll
        for (int ks = 0; ks < 2; ++ks) {
            const int k0 = ks * 32 + lk * 8;
            float v[8];
            float4 aa, bb;
            aa = *(const float4*)(Whh0 + n * 64 + k0); bb = *(const float4*)(Whh0 + n * 64 + k0 + 4);
            v[0]=aa.x; v[1]=aa.y; v[2]=aa.z; v[3]=aa.w; v[4]=bb.x; v[5]=bb.y; v[6]=bb.z; v[7]=bb.w;
#pragma unroll
            for (int e = 0; e < 8; ++e) { unsigned short hb=f2bf(v[e]); w0h[gi][ks][e]=(short)hb; w0l[gi][ks][e]=(short)f2bf(v[e]-bf2f(hb)); }
            aa = *(const float4*)(Wih1 + n * 64 + k0); bb = *(const float4*)(Wih1 + n * 64 + k0 + 4);
            v[0]=aa.x; v[1]=aa.y; v[2]=aa.z; v[3]=aa.w; v[4]=bb.x; v[5]=bb.y; v[6]=bb.z; v[7]=bb.w;
#pragma unroll
            for (int e = 0; e < 8; ++e) { unsigned short hb=f2bf(v[e]); w1h[gi][ks][e]=(short)hb; w1l[gi][ks][e]=(short)f2bf(v[e]-bf2f(hb)); }
            aa = *(const float4*)(Whh1 + n * 64 + k0); bb = *(const float4*)(Whh1 + n * 64 + k0 + 4);
            v[0]=aa.x; v[1]=aa.y; v[2]=aa.z; v[3]=aa.w; v[4]=bb.x; v[5]=bb.y; v[6]=bb.z; v[7]=bb.w;
#pragma unroll
            for (int e = 0; e < 8; ++e) { unsigned short hb=f2bf(v[e]); w2h[gi][ks][e]=(short)hb; w2l[gi][ks][e]=(short)f2bf(v[e]-bf2f(hb)); }
        }
    }

    // layer-1 bias per gate-tile
    float b1[4];
#pragma unroll
    for (int gi = 0; gi < 4; ++gi) { const int n = (w + 4 * gi) * 16 + lm; b1[gi] = bih1[n] + bhh1[n]; }

    // pre0 row pointers: row = batch (bbase + lk*4 + r), col base = 16w+lm
    const float* prow[4];
#pragma unroll
    for (int r = 0; r < 4; ++r)
        prow[r] = pre + (size_t)(bbase + lk * 4 + r) * (TSTEPS * 256) + (16 * w + lm);

    facc pcv[4];
#pragma unroll
    for (int gi = 0; gi < 4; ++gi)
#pragma unroll
        for (int r = 0; r < 4; ++r) pcv[gi][r] = prow[r][64 * gi];   // t=0

    float c0s[4] = {0,0,0,0}, c1s[4] = {0,0,0,0};
    float h1keep[4] = {0,0,0,0};

    const int j   = 16 * w + lm;       // hidden col this lane owns
    const int ksw = j >> 5;
    const int sub = (j >> 3) & 3;
    const int ew  = j & 7;

    int p = 0;
    __syncthreads();

#pragma unroll 1
    for (int t = 0; t < TSTEPS; ++t) {
        // prefetch pre0 for t+1
        facc pnv[4];
        if (t + 1 < TSTEPS) {
#pragma unroll
            for (int gi = 0; gi < 4; ++gi)
#pragma unroll
                for (int r = 0; r < 4; ++r) pnv[gi][r] = prow[r][(t + 1) * 256 + 64 * gi];
        }

        // ---- layer 0: z = pre0 + Whh0 . h0 ----
        bfrag a0h[2], a0l[2];
#pragma unroll
        for (int ks = 0; ks < 2; ++ks) {
            a0h[ks] = *(const bfrag*)&hbuf0[p][0][ks][lane][0];
            a0l[ks] = *(const bfrag*)&hbuf0[p][1][ks][lane][0];
        }
        facc z0[4];
#pragma unroll
        for (int gi = 0; gi < 4; ++gi) {
            facc z = pcv[gi];
            z = MFMA(a0h[0], w0h[gi][0], z);
            z = MFMA(a0l[0], w0h[gi][0], z);
            z = MFMA(a0h[0], w0l[gi][0], z);
            z = MFMA(a0h[1], w0h[gi][1], z);
            z = MFMA(a0l[1], w0h[gi][1], z);
            z = MFMA(a0h[1], w0l[gi][1], z);
            z0[gi] = z;
        }
        // gates layer 0 (lane holds all 4 gates of (m, j) for 4 batches)
#pragma unroll
        for (int r = 0; r < 4; ++r) {
            float i_ = sigf(z0[0][r]);
            float f_ = sigf(z0[1][r]);
            float g_ = tanh_fast(z0[2][r]);
            float o_ = sigf(z0[3][r]);
            c0s[r] = fmaf(f_, c0s[r], i_ * g_);
            float h = o_ * tanh_fast(c0s[r]);
            unsigned short hb = f2bf(h);
            hbuf0[p ^ 1][0][ksw][lk * 4 + r + 16 * sub][ew] = (short)hb;
            hbuf0[p ^ 1][1][ksw][lk * 4 + r + 16 * sub][ew] = (short)f2bf(h - bf2f(hb));
        }
        __syncthreads();

        // ---- layer 1: z = b1 + Wih1 . h0(t) + Whh1 . h1(t-1) ----
        bfrag x0h[2], x0l[2], a1h[2], a1l[2];
#pragma unroll
        for (int ks = 0; ks < 2; ++ks) {
            x0h[ks] = *(const bfrag*)&hbuf0[p ^ 1][0][ks][lane][0];
            x0l[ks] = *(const bfrag*)&hbuf0[p ^ 1][1][ks][lane][0];
            a1h[ks] = *(const bfrag*)&hbuf1[p][0][ks][lane][0];
            a1l[ks] = *(const bfrag*)&hbuf1[p][1][ks][lane][0];
        }
        facc z1[4];
#pragma unroll
        for (int gi = 0; gi < 4; ++gi) {
            facc z = { b1[gi], b1[gi], b1[gi], b1[gi] };
            z = MFMA(x0h[0], w1h[gi][0], z);
            z = MFMA(x0l[0], w1h[gi][0], z);
            z = MFMA(x0h[0], w1l[gi][0], z);
            z = MFMA(x0h[1], w1h[gi][1], z);
            z = MFMA(x0l[1], w1h[gi][1], z);
            z = MFMA(x0h[1], w1l[gi][1], z);
            z = MFMA(a1h[0], w2h[gi][0], z);
            z = MFMA(a1l[0], w2h[gi][0], z);
            z = MFMA(a1h[0], w2l[gi][0], z);
            z = MFMA(a1h[1], w2h[gi][1], z);
            z = MFMA(a1l[1], w2h[gi][1], z);
            z = MFMA(a1h[1], w2l[gi][1], z);
            z1[gi] = z;
        }
#pragma unroll
        for (int r = 0; r < 4; ++r) {
            float i_ = sigf(z1[0][r]);
            float f_ = sigf(z1[1][r]);
            float g_ = tanh_fast(z1[2][r]);
            float o_ = sigf(z1[3][r]);
            c1s[r] = fmaf(f_, c1s[r], i_ * g_);
            float h = o_ * tanh_fast(c1s[r]);
            h1keep[r] = h;
            unsigned short hb = f2bf(h);
            hbuf1[p ^ 1][0][ksw][lk * 4 + r + 16 * sub][ew] = (short)hb;
            hbuf1[p ^ 1][1][ksw][lk * 4 + r + 16 * sub][ew] = (short)f2bf(h - bf2f(hb));
        }
        __syncthreads();

        p ^= 1;
#pragma unroll
        for (int gi = 0; gi < 4; ++gi) pcv[gi] = pnv[gi];
    }

    // ---- head: out[b] = h1 . Wfc + bfc ----
#pragma unroll
    for (int r = 0; r < 4; ++r) hfin[lk * 4 + r][j] = h1keep[r];
    __syncthreads();
    {
        const int m = tid >> 4, q = tid & 15;
        float s = 0.0f;
#pragma unroll
        for (int d = 0; d < 4; ++d) s = fmaf(hfin[m][q * 4 + d], Wfc[q * 4 + d], s);
        psum[m][q] = s;
    }
    __syncthreads();
    if (tid < 16) {
        float s = 0.0f;
#pragma unroll
        for (int q = 0; q < 16; ++q) s += psum[tid][q];
        out[bbase + tid] = s + bfc[0];
    }
}

extern "C" void kernel_launch(void* const* d_in, const int* in_sizes, int n_in,
                              void* d_out, int out_size, void* d_ws, size_t ws_size,
                              hipStream_t stream)
{
    const float* x    = (const float*)d_in[0];
    const float* Wih0 = (const float*)d_in[1];
    const float* Whh0 = (const float*)d_in[2];
    const float* bih0 = (const float*)d_in[3];
    const float* bhh0 = (const float*)d_in[4];
    const float* Wih1 = (const float*)d_in[5];
    const float* Whh1 = (const float*)d_in[6];
    const float* bih1 = (const float*)d_in[7];
    const float* bhh1 = (const float*)d_in[8];
    const float* Wfc  = (const float*)d_in[9];
    const float* bfc  = (const float*)d_in[10];
    float* out = (float*)d_out;
    float* pre = (float*)d_ws;  // [B][T][256] fp32 = 256 MiB

    k_inproj<<<4096, 256, 0, stream>>>(x, Wih0, bih0, bhh0, pre);
    k_fused<<<32, 256, 0, stream>>>(Whh0, Wih1, Whh1, bih1, bhh1, Wfc, bfc, pre, out);
}

// Round 6
// 1155.657 us; speedup vs baseline: 1.5315x; 1.5315x over previous
//
#include <hip/hip_runtime.h>

// LSTM B=512,T=512,D=128,H=64,O=1. Gate order i,f,g,o.
// K1: pre[b][t][g] = x[b,t,:]@Wih0^T + bih0+bhh0  (fp32 register-tiled GEMM).
// K2: fused 2-layer recurrence, pure fp32 VALU.
//   512 blocks (1 batch elem) x 256 thr. Thread = (hidden unit j=tid>>2,
//   k-quarter qt=tid&3). Its 4 output cols are the 4 GATES of unit j, so after
//   a 2-step quad butterfly (shfl_xor 1,2) each thread holds i,f,g,o of unit j
//   -> cell update fully in-register, c-state per thread, no gate LDS round-trip.
//   Weights (3 mats x 4 gates x 16 k = 192 floats/thread) are pinned in VGPRs
//   with asm "+v" — Rounds 3/4 showed the allocator demotes plain loop-invariant
//   weight loads to per-step L2 re-fetches (VGPR=80/44 vs 128/48 declared).
//   launch_bounds(256,2) => VGPR cap 256, 2 blocks/CU co-resident.
// ws: 512*512*256*4 = 256 MiB fp32 pre buffer (read-only in K2).

#define TSTEPS 512

__device__ __forceinline__ float sigf(float x){ return 1.0f/(1.0f+__expf(-x)); }
__device__ __forceinline__ float tanh_fast(float x){
  float ax=fabsf(x); float e=__expf(-2.0f*ax); float r=(1.0f-e)/(1.0f+e); return copysignf(r,x);
}
#define KEEP(x) asm volatile("" : "+v"(x))

// ---------------- K1: input projection GEMM (fp32 VALU) ----------------
__global__ __launch_bounds__(256) void k_inproj(
    const float* __restrict__ x, const float* __restrict__ W,
    const float* __restrict__ bih, const float* __restrict__ bhh,
    float* __restrict__ pre)
{
    __shared__ float xs[64][128];
    const int tid = threadIdx.x;
    const long row0 = (long)blockIdx.x * 64;

    const float4* __restrict__ xv = (const float4*)(x + row0 * 128);
    float4* xsv = (float4*)(&xs[0][0]);
#pragma unroll
    for (int i = 0; i < 8; ++i) xsv[tid + 256 * i] = xv[tid + 256 * i];
    __syncthreads();

    const int tx = tid & 63;
    const int ty = tid >> 6;

    float acc[16][4];
#pragma unroll
    for (int i = 0; i < 16; ++i)
#pragma unroll
        for (int j = 0; j < 4; ++j) acc[i][j] = 0.0f;

#pragma unroll 1
    for (int kc = 0; kc < 16; ++kc) {
        const int k0 = kc * 8;
        float4 w0[4], w1[4];
#pragma unroll
        for (int j = 0; j < 4; ++j) {
            const float* wr = W + (tx + 64 * j) * 128 + k0;
            w0[j] = *(const float4*)wr;
            w1[j] = *(const float4*)(wr + 4);
        }
#pragma unroll
        for (int i = 0; i < 16; ++i) {
            const int r = ty * 16 + i;
            float4 a0 = *(const float4*)(&xs[r][k0]);
            float4 a1 = *(const float4*)(&xs[r][k0 + 4]);
#pragma unroll
            for (int j = 0; j < 4; ++j) {
                float s = acc[i][j];
                s = fmaf(a0.x, w0[j].x, s); s = fmaf(a0.y, w0[j].y, s);
                s = fmaf(a0.z, w0[j].z, s); s = fmaf(a0.w, w0[j].w, s);
                s = fmaf(a1.x, w1[j].x, s); s = fmaf(a1.y, w1[j].y, s);
                s = fmaf(a1.z, w1[j].z, s); s = fmaf(a1.w, w1[j].w, s);
                acc[i][j] = s;
            }
        }
    }

    float bsum[4];
#pragma unroll
    for (int j = 0; j < 4; ++j) { const int g = tx + 64 * j; bsum[j] = bih[g] + bhh[g]; }
#pragma unroll
    for (int i = 0; i < 16; ++i) {
        const long r = row0 + ty * 16 + i;
        float* pr = pre + r * 256;
#pragma unroll
        for (int j = 0; j < 4; ++j) pr[tx + 64 * j] = acc[i][j] + bsum[j];
    }
}

// ---------------- K2: fused 2-layer recurrence + head ----------------
__global__ __launch_bounds__(256, 2) void k_fused(
    const float* __restrict__ Whh0, const float* __restrict__ Wih1,
    const float* __restrict__ Whh1,
    const float* __restrict__ bih1, const float* __restrict__ bhh1,
    const float* __restrict__ Wfc,  const float* __restrict__ bfc,
    const float* __restrict__ pre,  float* __restrict__ out)
{
    const int tid = threadIdx.x;
    const int j  = tid >> 2;   // hidden unit 0..63
    const int qt = tid & 3;    // k-quarter 0..3
    const int b  = blockIdx.x;

    __shared__ __align__(16) float h0s[2][64];
    __shared__ __align__(16) float h1s[2][64];

    // weights: gate gi of unit j, k-slice [qt*16, qt*16+16)
    float w0[4][16], w1[4][16], w2[4][16];
    float bias1v[4];
#pragma unroll
    for (int gi = 0; gi < 4; ++gi) {
        const int row = 64 * gi + j;
        const float4* a = (const float4*)(Whh0 + row * 64 + qt * 16);
        const float4* c = (const float4*)(Wih1 + row * 64 + qt * 16);
        const float4* d = (const float4*)(Whh1 + row * 64 + qt * 16);
#pragma unroll
        for (int i = 0; i < 4; ++i) {
            float4 va = a[i], vc = c[i], vd = d[i];
            w0[gi][4*i+0] = va.x; w0[gi][4*i+1] = va.y; w0[gi][4*i+2] = va.z; w0[gi][4*i+3] = va.w;
            w1[gi][4*i+0] = vc.x; w1[gi][4*i+1] = vc.y; w1[gi][4*i+2] = vc.z; w1[gi][4*i+3] = vc.w;
            w2[gi][4*i+0] = vd.x; w2[gi][4*i+1] = vd.y; w2[gi][4*i+2] = vd.z; w2[gi][4*i+3] = vd.w;
        }
        bias1v[gi] = bih1[row] + bhh1[row];
    }
    // pin weights in VGPRs: opaque defs — cannot be rematerialized from memory
#pragma unroll
    for (int gi = 0; gi < 4; ++gi)
#pragma unroll
        for (int k = 0; k < 16; ++k) { KEEP(w0[gi][k]); KEEP(w1[gi][k]); KEEP(w2[gi][k]); }

    if (tid < 64) { h0s[0][tid] = 0.0f; h1s[0][tid] = 0.0f; }
    float c0 = 0.0f, c1 = 0.0f;

    const float* __restrict__ pb = pre + (size_t)b * TSTEPS * 256 + j;
    float pc[4];
#pragma unroll
    for (int gi = 0; gi < 4; ++gi) pc[gi] = pb[64 * gi];   // t=0 (quad lanes dup -> coalesced)
    int p = 0;
    __syncthreads();

#pragma unroll 1
    for (int t = 0; t < TSTEPS; ++t) {
        // prefetch pre0 for t+1
        float pn[4];
        const int tn = (t + 1 < TSTEPS) ? (t + 1) : t;
#pragma unroll
        for (int gi = 0; gi < 4; ++gi) pn[gi] = pb[tn * 256 + 64 * gi];

        // phase-1 LDS reads: h0_{t-1}, h1_{t-1} quarter-slices
        float h0q[16], h1q[16];
        {
            const float4* h0f = (const float4*)&h0s[p][qt * 16];
            const float4* h1f = (const float4*)&h1s[p][qt * 16];
#pragma unroll
            for (int i = 0; i < 4; ++i) {
                float4 v0 = h0f[i], v1 = h1f[i];
                h0q[4*i+0]=v0.x; h0q[4*i+1]=v0.y; h0q[4*i+2]=v0.z; h0q[4*i+3]=v0.w;
                h1q[4*i+0]=v1.x; h1q[4*i+1]=v1.y; h1q[4*i+2]=v1.z; h1q[4*i+3]=v1.w;
            }
        }

        // ---- layer 0 ----
        float z0[4];
#pragma unroll
        for (int gi = 0; gi < 4; ++gi) {
            float s = 0.0f;
#pragma unroll
            for (int k = 0; k < 16; ++k) s = fmaf(w0[gi][k], h0q[k], s);
            s += __shfl_xor(s, 1); s += __shfl_xor(s, 2);   // quad butterfly: full 64-sum
            z0[gi] = pc[gi] + s;
        }
        {
            float i_ = sigf(z0[0]), f_ = sigf(z0[1]), g_ = tanh_fast(z0[2]), o_ = sigf(z0[3]);
            c0 = fmaf(f_, c0, i_ * g_);
            float h0n = o_ * tanh_fast(c0);
            if (qt == 0) h0s[p ^ 1][j] = h0n;
        }
        __syncthreads();

        // ---- layer 1: needs h0_t (just written) + h1_{t-1} (read in phase 1) ----
        float h0nq[16];
        {
            const float4* hf = (const float4*)&h0s[p ^ 1][qt * 16];
#pragma unroll
            for (int i = 0; i < 4; ++i) {
                float4 v = hf[i];
                h0nq[4*i+0]=v.x; h0nq[4*i+1]=v.y; h0nq[4*i+2]=v.z; h0nq[4*i+3]=v.w;
            }
        }
        float z1[4];
#pragma unroll
        for (int gi = 0; gi < 4; ++gi) {
            float s = 0.0f;
#pragma unroll
            for (int k = 0; k < 16; ++k) s = fmaf(w1[gi][k], h0nq[k], s);
#pragma unroll
            for (int k = 0; k < 16; ++k) s = fmaf(w2[gi][k], h1q[k], s);
            s += __shfl_xor(s, 1); s += __shfl_xor(s, 2);
            z1[gi] = bias1v[gi] + s;
        }
        {
            float i_ = sigf(z1[0]), f_ = sigf(z1[1]), g_ = tanh_fast(z1[2]), o_ = sigf(z1[3]);
            c1 = fmaf(f_, c1, i_ * g_);
            float h1n = o_ * tanh_fast(c1);
            if (qt == 0) h1s[p ^ 1][j] = h1n;
        }
        __syncthreads();

        p ^= 1;
#pragma unroll
        for (int gi = 0; gi < 4; ++gi) pc[gi] = pn[gi];
    }

    // ---- head: out[b] = h1_{T-1} . Wfc + bfc  (wave 0) ----
    if (tid < 64) {
        float v = h1s[p][tid] * Wfc[tid];
#pragma unroll
        for (int off = 32; off > 0; off >>= 1) v += __shfl_down(v, off);
        if (tid == 0) out[b] = v + bfc[0];
    }
}

extern "C" void kernel_launch(void* const* d_in, const int* in_sizes, int n_in,
                              void* d_out, int out_size, void* d_ws, size_t ws_size,
                              hipStream_t stream)
{
    const float* x    = (const float*)d_in[0];
    const float* Wih0 = (const float*)d_in[1];
    const float* Whh0 = (const float*)d_in[2];
    const float* bih0 = (const float*)d_in[3];
    const float* bhh0 = (const float*)d_in[4];
    const float* Wih1 = (const float*)d_in[5];
    const float* Whh1 = (const float*)d_in[6];
    const float* bih1 = (const float*)d_in[7];
    const float* bhh1 = (const float*)d_in[8];
    const float* Wfc  = (const float*)d_in[9];
    const float* bfc  = (const float*)d_in[10];
    float* out = (float*)d_out;
    float* pre = (float*)d_ws;  // [B][T][256] fp32 = 256 MiB

    k_inproj<<<4096, 256, 0, stream>>>(x, Wih0, bih0, bhh0, pre);
    k_fused<<<512, 256, 0, stream>>>(Whh0, Wih1, Whh1, bih1, bhh1, Wfc, bfc, pre, out);
}